// Round 2
// baseline (691.351 us; speedup 1.0000x reference)
//
#include <hip/hip_runtime.h>

#define B_   32
#define C_   64
#define T_   300
#define J_   25
#define K9   9
constexpr int PLANE = T_ * J_;           // 7500
constexpr int BCTJ  = B_ * C_ * PLANE;   // 15,360,000
constexpr float BN_EPS = 1e-5f;
constexpr float BN_N   = (float)(B_ * T_ * J_);  // 240000

typedef __attribute__((ext_vector_type(8))) short bf16x8;
typedef __attribute__((ext_vector_type(4))) float f32x4;

__device__ inline unsigned short f2bf(float f) {
  unsigned u = __float_as_uint(f);
  unsigned r = (u + 0x7FFF + ((u >> 16) & 1)) >> 16;
  return (unsigned short)r;
}

// ---------------------------------------------------------------------------
// K0: tcn_w [o][c][kt] -> Wb[kt][o][c] bf16
__global__ __launch_bounds__(256) void wb_kernel(const float* __restrict__ w,
                                                 unsigned short* __restrict__ Wb) {
  int idx = blockIdx.x * 256 + threadIdx.x;
  if (idx < C_ * C_ * K9) {
    int o = idx / (C_ * K9);
    int rem = idx % (C_ * K9);
    int c = rem / K9, kt = rem % K9;
    Wb[kt * (C_ * C_) + o * C_ + c] = f2bf(w[idx]);
  }
}

// ---------------------------------------------------------------------------
// K1: GCN (unchanged)
__global__ __launch_bounds__(256) void gcn_kernel(
    const float* __restrict__ x, const float* __restrict__ A,
    const float* __restrict__ W, const float* __restrict__ bias,
    float* __restrict__ y1) {
  __shared__ float As[J_ * J_];
  __shared__ float Ws[C_ * C_];
  __shared__ float Xs[C_ * J_];
  __shared__ float XAs[C_ * J_];
  int bid = blockIdx.x;
  int b = bid / T_, t = bid % T_;
  size_t base = (size_t)b * (C_ * PLANE) + (size_t)t * J_;

  for (int i = threadIdx.x; i < J_ * J_; i += 256) As[i] = A[i];
  for (int i = threadIdx.x; i < C_ * C_; i += 256) Ws[i] = W[i];
  for (int i = threadIdx.x; i < C_ * J_; i += 256) {
    int c = i / J_, j = i % J_;
    Xs[i] = x[base + (size_t)c * PLANE + j];
  }
  __syncthreads();
  for (int i = threadIdx.x; i < C_ * J_; i += 256) {
    int c = i / J_, k = i % J_;
    float s = 0.f;
#pragma unroll
    for (int j = 0; j < J_; ++j) s = fmaf(Xs[c * J_ + j], As[j * J_ + k], s);
    XAs[i] = s;
  }
  __syncthreads();
  for (int i = threadIdx.x; i < C_ * J_; i += 256) {
    int o = i / J_, k = i % J_;
    float s = bias[o];
#pragma unroll
    for (int c = 0; c < C_; ++c) s = fmaf(Ws[o * C_ + c], XAs[c * J_ + k], s);
    y1[base + (size_t)o * PLANE + k] = s;
  }
}

// ---------------------------------------------------------------------------
// K2: per-channel sum / sumsq over one (b,c) plane (used for BN1 only now)
__global__ __launch_bounds__(256) void stats_kernel(const float* __restrict__ in,
                                                    float* __restrict__ stats) {
  int bc = blockIdx.x;
  int c = bc & (C_ - 1);
  const float4* p4 = (const float4*)(in + (size_t)bc * PLANE);
  float s = 0.f, sq = 0.f;
  for (int i = threadIdx.x; i < PLANE / 4; i += 256) {
    float4 v = p4[i];
    s += v.x + v.y + v.z + v.w;
    sq += v.x * v.x + v.y * v.y + v.z * v.z + v.w * v.w;
  }
#pragma unroll
  for (int off = 32; off > 0; off >>= 1) {
    s += __shfl_down(s, off);
    sq += __shfl_down(sq, off);
  }
  __shared__ float ls[2][4];
  int wave = threadIdx.x >> 6, lane = threadIdx.x & 63;
  if (lane == 0) { ls[0][wave] = s; ls[1][wave] = sq; }
  __syncthreads();
  if (threadIdx.x == 0) {
    atomicAdd(&stats[c], ls[0][0] + ls[0][1] + ls[0][2] + ls[0][3]);
    atomicAdd(&stats[C_ + c], ls[1][0] + ls[1][1] + ls[1][2] + ls[1][3]);
  }
}

// ---------------------------------------------------------------------------
// K3: finalize BN params
__global__ void bnparam_kernel(const float* __restrict__ stats,
                               const float* __restrict__ g,
                               const float* __restrict__ b,
                               float* __restrict__ bnp) {
  int c = threadIdx.x;
  if (c < C_) {
    float mean = stats[c] / BN_N;
    float var = stats[C_ + c] / BN_N - mean * mean;
    float inv = rsqrtf(var + BN_EPS);
    float sc = g[c] * inv;
    bnp[c] = sc;
    bnp[C_ + c] = b[c] - mean * sc;
  }
}

// ---------------------------------------------------------------------------
// K4: MFMA temporal conv.  Per block (b, 10-t tile):
//  zs[row=(trow,jj)][c] bf16, rows 0..449 = relu(bn1(y1)) with 4-row halo,
//  rows 450..455 zero.  XOR swizzle: elem idx ^= (row&7)<<3.
//  GEMM: y2[o, n] = sum_{kt,c} Wb[kt][o][c] * zs[n+25kt][c],  n = tl*25+j.
//  Epilogue adds bias, writes y2, and shuffle-reduces BN2 sum/sumsq.
constexpr int TT = 10;
constexpr int ZROWS_TOT = 456;           // 450 data + 6 zero pad (cols 250..255)
__global__ __launch_bounds__(256) void tcn_mfma_kernel(
    const float* __restrict__ y1, const unsigned short* __restrict__ Wb,
    const float* __restrict__ bnp1, const float* __restrict__ tbias,
    float* __restrict__ y2, float* __restrict__ stats2) {
  __shared__ unsigned short zs[ZROWS_TOT * C_];   // 58368 B
  int bid = blockIdx.x;
  int b = bid / (T_ / TT), tile = bid % (T_ / TT);
  int t0 = tile * TT;
  size_t bbase = (size_t)b * (C_ * PLANE);
  int tid = threadIdx.x;

  // ---- stage z = relu(bn1(y1)) as bf16, swizzled ----
  int rlo = (t0 == 0) ? 100 : 0;                       // r >= (4-t0)*25
  int rhi = min(450, (304 - t0) * 25);                 // r < 7600-25*t0
  const float* ysrc = y1 + bbase + (ptrdiff_t)(t0 - 4) * J_;
  for (int u = tid; u < C_ * 225; u += 256) {
    int c = u / 225, r = (u % 225) * 2;
    float sc = bnp1[c], sh = bnp1[C_ + c];
    const float* p = ysrc + (ptrdiff_t)c * PLANE + r;
    float v0, v1;
    if (r >= rlo && r + 1 < rhi) {
      float2 tv = *(const float2*)p; v0 = tv.x; v1 = tv.y;
    } else {
      v0 = (r >= rlo && r < rhi) ? p[0] : 0.f;
      v1 = (r + 1 >= rlo && r + 1 < rhi) ? p[1] : 0.f;
    }
    float z0 = fmaxf(fmaf(v0, sc, sh), 0.f);
    float z1 = fmaxf(fmaf(v1, sc, sh), 0.f);
    zs[((r << 6) | c) ^ ((r & 7) << 3)] = f2bf(z0);
    zs[(((r + 1) << 6) | c) ^ (((r + 1) & 7) << 3)] = f2bf(z1);
  }
  for (int u = tid; u < 6 * C_; u += 256) {
    int r = 450 + u / C_, c = u % C_;
    zs[((r << 6) | c) ^ ((r & 7) << 3)] = 0;
  }
  __syncthreads();

  // ---- MFMA main loop ----
  int l = tid & 63, w = tid >> 6;
  int lr = l & 15, lh = l >> 4;
  int n0 = w * 64;
  f32x4 acc[4][4];
#pragma unroll
  for (int mf = 0; mf < 4; ++mf)
#pragma unroll
    for (int nf = 0; nf < 4; ++nf) acc[mf][nf] = (f32x4)0.f;

#pragma unroll
  for (int kt = 0; kt < K9; ++kt) {
    bf16x8 af[4][2];
#pragma unroll
    for (int mf = 0; mf < 4; ++mf) {
      const unsigned short* wp = Wb + kt * (C_ * C_) + (mf * 16 + lr) * C_ + lh * 8;
      af[mf][0] = *(const bf16x8*)(wp);
      af[mf][1] = *(const bf16x8*)(wp + 32);
    }
    bf16x8 bfr[4][2];
#pragma unroll
    for (int nf = 0; nf < 4; ++nf) {
      int r = n0 + nf * 16 + lr + 25 * kt;
      int sw = (r & 7) << 3;
      bfr[nf][0] = *(const bf16x8*)&zs[((r << 6) | (lh * 8)) ^ sw];
      bfr[nf][1] = *(const bf16x8*)&zs[((r << 6) | (32 + lh * 8)) ^ sw];
    }
#pragma unroll
    for (int mf = 0; mf < 4; ++mf)
#pragma unroll
      for (int nf = 0; nf < 4; ++nf) {
        acc[mf][nf] = __builtin_amdgcn_mfma_f32_16x16x32_bf16(af[mf][0], bfr[nf][0], acc[mf][nf], 0, 0, 0);
        acc[mf][nf] = __builtin_amdgcn_mfma_f32_16x16x32_bf16(af[mf][1], bfr[nf][1], acc[mf][nf], 0, 0, 0);
      }
  }

  // ---- epilogue: bias, store, fused BN2 stats ----
  size_t obase = bbase + (size_t)t0 * J_;
#pragma unroll
  for (int mf = 0; mf < 4; ++mf) {
    float4 tb4 = *(const float4*)(tbias + mf * 16 + 4 * lh);
#pragma unroll
    for (int reg = 0; reg < 4; ++reg) {
      int o = mf * 16 + 4 * lh + reg;
      float s = 0.f, q = 0.f;
#pragma unroll
      for (int nf = 0; nf < 4; ++nf) {
        int n = n0 + nf * 16 + lr;
        float v = acc[mf][nf][reg] + ((const float*)&tb4)[reg];
        if (n < 250) {
          y2[obase + (size_t)o * PLANE + n] = v;
          s += v; q += v * v;
        }
      }
#pragma unroll
      for (int m = 1; m < 16; m <<= 1) {
        s += __shfl_xor(s, m);
        q += __shfl_xor(q, m);
      }
      if (lr == 0) {
        atomicAdd(&stats2[o], s);
        atomicAdd(&stats2[C_ + o], q);
      }
    }
  }
}

// ---------------------------------------------------------------------------
// K5: out = relu(bn2(y2) + x), in place on d_out
__global__ __launch_bounds__(256) void final_kernel(float* __restrict__ y2,
                                                    const float* __restrict__ x,
                                                    const float* __restrict__ bnp2) {
  int i = blockIdx.x * 256 + threadIdx.x;
  if (i >= BCTJ / 4) return;
  int c = (i / (PLANE / 4)) & (C_ - 1);
  float sc = bnp2[c], sh = bnp2[C_ + c];
  float4 v = ((const float4*)y2)[i];
  float4 xv = ((const float4*)x)[i];
  v.x = fmaxf(fmaf(v.x, sc, sh) + xv.x, 0.f);
  v.y = fmaxf(fmaf(v.y, sc, sh) + xv.y, 0.f);
  v.z = fmaxf(fmaf(v.z, sc, sh) + xv.z, 0.f);
  v.w = fmaxf(fmaf(v.w, sc, sh) + xv.w, 0.f);
  ((float4*)y2)[i] = v;
}

// ---------------------------------------------------------------------------
extern "C" void kernel_launch(void* const* d_in, const int* in_sizes, int n_in,
                              void* d_out, int out_size, void* d_ws, size_t ws_size,
                              hipStream_t stream) {
  const float* x     = (const float*)d_in[0];
  const float* A     = (const float*)d_in[1];
  const float* gcn_w = (const float*)d_in[2];
  const float* gcn_b = (const float*)d_in[3];
  const float* bn1_g = (const float*)d_in[4];
  const float* bn1_b = (const float*)d_in[5];
  const float* tcn_w = (const float*)d_in[6];
  const float* tcn_b = (const float*)d_in[7];
  const float* bn2_g = (const float*)d_in[8];
  const float* bn2_b = (const float*)d_in[9];
  float* out = (float*)d_out;

  float* y1 = (float*)d_ws;                               // 15,360,000 f32
  unsigned short* Wb = (unsigned short*)(y1 + BCTJ);      // 36,864 bf16
  float* stats = (float*)(Wb + C_ * C_ * K9);             // 256 f32
  float* bnp   = stats + 256;                             // 256 f32

  hipMemsetAsync(stats, 0, 256 * sizeof(float), stream);
  wb_kernel<<<(C_ * C_ * K9 + 255) / 256, 256, 0, stream>>>(tcn_w, Wb);
  gcn_kernel<<<B_ * T_, 256, 0, stream>>>(x, A, gcn_w, gcn_b, y1);
  stats_kernel<<<B_ * C_, 256, 0, stream>>>(y1, stats);
  bnparam_kernel<<<1, 64, 0, stream>>>(stats, bn1_g, bn1_b, bnp);
  tcn_mfma_kernel<<<B_ * (T_ / TT), 256, 0, stream>>>(y1, Wb, bnp, tcn_b, out, stats + 128);
  bnparam_kernel<<<1, 64, 0, stream>>>(stats + 128, bn2_g, bn2_b, bnp + 128);
  final_kernel<<<BCTJ / 4 / 256, 256, 0, stream>>>(out, x, bnp + 128);
}

// Round 3
// 300.765 us; speedup vs baseline: 2.2986x; 2.2986x over previous
//
#include <hip/hip_runtime.h>

#define B_   32
#define C_   64
#define T_   300
#define J_   25
#define K9   9
constexpr int PLANE = T_ * J_;           // 7500
constexpr int BCTJ  = B_ * C_ * PLANE;   // 15,360,000
constexpr float BN_EPS = 1e-5f;
constexpr float BN_N   = (float)(B_ * T_ * J_);  // 240000

typedef __attribute__((ext_vector_type(8))) short bf16x8;
typedef __attribute__((ext_vector_type(4))) float f32x4;

__device__ inline unsigned short f2bf(float f) {
  unsigned u = __float_as_uint(f);
  unsigned r = (u + 0x7FFF + ((u >> 16) & 1)) >> 16;
  return (unsigned short)r;
}
__device__ inline float bf2f(unsigned short h) {
  return __uint_as_float(((unsigned)h) << 16);
}

// ---------------------------------------------------------------------------
// K0: weight prep. idx<36864: tcn_w [o][c][kt] -> Wb[kt][o][c] bf16.
//     next 4096: gcn_w [o][c] -> Gb[o][c] bf16.
__global__ __launch_bounds__(256) void prep_kernel(const float* __restrict__ tw,
                                                   const float* __restrict__ gw,
                                                   unsigned short* __restrict__ Wb,
                                                   unsigned short* __restrict__ Gb) {
  int idx = blockIdx.x * 256 + threadIdx.x;
  if (idx < C_ * C_ * K9) {
    int o = idx / (C_ * K9);
    int rem = idx % (C_ * K9);
    int c = rem / K9, kt = rem % K9;
    Wb[kt * (C_ * C_) + o * C_ + c] = f2bf(tw[idx]);
  } else if (idx < C_ * C_ * K9 + C_ * C_) {
    int i = idx - C_ * C_ * K9;
    Gb[i] = f2bf(gw[i]);
  }
}

// ---------------------------------------------------------------------------
// K1: GCN via MFMA. Block = (b, 10-t tile) -> 250 output cols.
//  stage x bf16 [c][250]; VALU j-mix -> XAs bf16 swizzled [row n][c];
//  MFMA: y1[o,n] = sum_c Gb[o,c] * XA[c,n] + gcn_b[o].
constexpr int TTG = 10;
__global__ __launch_bounds__(256) void gcn_mfma_kernel(
    const float* __restrict__ x, const float* __restrict__ A,
    const unsigned short* __restrict__ Gb, const float* __restrict__ gbias,
    float* __restrict__ y1) {
  __shared__ unsigned short Xs[C_ * 250];     // 32000 B
  __shared__ unsigned short XAs[256 * C_];    // 32768 B, swizzled
  __shared__ float As[J_ * J_];               // 2500 B
  int bid = blockIdx.x;
  int b = bid / (T_ / TTG), tile = bid % (T_ / TTG);
  int t0 = tile * TTG;
  size_t bbase = (size_t)b * (C_ * PLANE);
  int tid = threadIdx.x;

  for (int i = tid; i < J_ * J_; i += 256) As[i] = A[i];
  const float* xsrc = x + bbase + (size_t)t0 * J_;
  for (int i = tid; i < C_ * 125; i += 256) {
    int c = i / 125, m = i % 125;
    float2 v = *(const float2*)(xsrc + (size_t)c * PLANE + 2 * m);
    unsigned p = (unsigned)f2bf(v.x) | ((unsigned)f2bf(v.y) << 16);
    ((unsigned*)Xs)[c * 125 + m] = p;
  }
  __syncthreads();

  // j-mix: XA[c][n] = sum_j x[c][tt*25+j] * A[j][k],  n = tt*25+k
  for (int i = tid; i < C_ * 250; i += 256) {
    int c = i / 250, n = i % 250;
    int tt = n / J_, k = n % J_;
    const unsigned short* xp = Xs + c * 250 + tt * J_;
    float s = 0.f;
#pragma unroll
    for (int j = 0; j < J_; ++j) s = fmaf(bf2f(xp[j]), As[j * J_ + k], s);
    XAs[((n << 6) | c) ^ ((n & 7) << 3)] = f2bf(s);
  }
  for (int i = tid; i < 6 * C_; i += 256) {
    int r = 250 + i / C_, c = i % C_;
    XAs[((r << 6) | c) ^ ((r & 7) << 3)] = 0;
  }
  __syncthreads();

  // MFMA: M=64 (o), N=256 (n), K=64 (c)
  int l = tid & 63, w = tid >> 6;
  int lr = l & 15, lh = l >> 4;
  int n0 = w * 64;
  f32x4 acc[4][4];
#pragma unroll
  for (int mf = 0; mf < 4; ++mf)
#pragma unroll
    for (int nf = 0; nf < 4; ++nf) acc[mf][nf] = (f32x4)0.f;

  bf16x8 af[4][2];
#pragma unroll
  for (int mf = 0; mf < 4; ++mf) {
    const unsigned short* wp = Gb + (mf * 16 + lr) * C_ + lh * 8;
    af[mf][0] = *(const bf16x8*)(wp);
    af[mf][1] = *(const bf16x8*)(wp + 32);
  }
  bf16x8 bfr[4][2];
#pragma unroll
  for (int nf = 0; nf < 4; ++nf) {
    int r = n0 + nf * 16 + lr;
    int sw = (r & 7) << 3;
    bfr[nf][0] = *(const bf16x8*)&XAs[((r << 6) | (lh * 8)) ^ sw];
    bfr[nf][1] = *(const bf16x8*)&XAs[((r << 6) | (32 + lh * 8)) ^ sw];
  }
#pragma unroll
  for (int mf = 0; mf < 4; ++mf)
#pragma unroll
    for (int nf = 0; nf < 4; ++nf) {
      acc[mf][nf] = __builtin_amdgcn_mfma_f32_16x16x32_bf16(af[mf][0], bfr[nf][0], acc[mf][nf], 0, 0, 0);
      acc[mf][nf] = __builtin_amdgcn_mfma_f32_16x16x32_bf16(af[mf][1], bfr[nf][1], acc[mf][nf], 0, 0, 0);
    }

  float* ydst = y1 + bbase + (size_t)t0 * J_;
#pragma unroll
  for (int mf = 0; mf < 4; ++mf) {
    float4 gb4 = *(const float4*)(gbias + mf * 16 + 4 * lh);
#pragma unroll
    for (int reg = 0; reg < 4; ++reg) {
      int o = mf * 16 + 4 * lh + reg;
#pragma unroll
      for (int nf = 0; nf < 4; ++nf) {
        int n = n0 + nf * 16 + lr;
        if (n < 250)
          ydst[(size_t)o * PLANE + n] = acc[mf][nf][reg] + ((const float*)&gb4)[reg];
      }
    }
  }
}

// ---------------------------------------------------------------------------
// K2: per-channel sum / sumsq over one (b,c) plane
__global__ __launch_bounds__(256) void stats_kernel(const float* __restrict__ in,
                                                    float* __restrict__ stats) {
  int bc = blockIdx.x;
  int c = bc & (C_ - 1);
  const float4* p4 = (const float4*)(in + (size_t)bc * PLANE);
  float s = 0.f, sq = 0.f;
  for (int i = threadIdx.x; i < PLANE / 4; i += 256) {
    float4 v = p4[i];
    s += v.x + v.y + v.z + v.w;
    sq += v.x * v.x + v.y * v.y + v.z * v.z + v.w * v.w;
  }
#pragma unroll
  for (int off = 32; off > 0; off >>= 1) {
    s += __shfl_down(s, off);
    sq += __shfl_down(sq, off);
  }
  __shared__ float ls[2][4];
  int wave = threadIdx.x >> 6, lane = threadIdx.x & 63;
  if (lane == 0) { ls[0][wave] = s; ls[1][wave] = sq; }
  __syncthreads();
  if (threadIdx.x == 0) {
    atomicAdd(&stats[c], ls[0][0] + ls[0][1] + ls[0][2] + ls[0][3]);
    atomicAdd(&stats[C_ + c], ls[1][0] + ls[1][1] + ls[1][2] + ls[1][3]);
  }
}

// ---------------------------------------------------------------------------
// K3: finalize BN params
__global__ void bnparam_kernel(const float* __restrict__ stats,
                               const float* __restrict__ g,
                               const float* __restrict__ b,
                               float* __restrict__ bnp) {
  int c = threadIdx.x;
  if (c < C_) {
    float mean = stats[c] / BN_N;
    float var = stats[C_ + c] / BN_N - mean * mean;
    float inv = rsqrtf(var + BN_EPS);
    float sc = g[c] * inv;
    bnp[c] = sc;
    bnp[C_ + c] = b[c] - mean * sc;
  }
}

// ---------------------------------------------------------------------------
// K4: MFMA temporal conv (no fused stats).  Correct zero halo padding.
constexpr int TT = 10;
constexpr int ZROWS_TOT = 456;           // 450 data + 6 zero pad
__global__ __launch_bounds__(256) void tcn_mfma_kernel(
    const float* __restrict__ y1, const unsigned short* __restrict__ Wb,
    const float* __restrict__ bnp1, const float* __restrict__ tbias,
    float* __restrict__ y2) {
  __shared__ unsigned short zs[ZROWS_TOT * C_];   // 58368 B
  int bid = blockIdx.x;
  int b = bid / (T_ / TT), tile = bid % (T_ / TT);
  int t0 = tile * TT;
  size_t bbase = (size_t)b * (C_ * PLANE);
  int tid = threadIdx.x;

  int rlo = (t0 == 0) ? 100 : 0;                       // r >= (4-t0)*25
  int rhi = min(450, (304 - t0) * 25);                 // r < (304-t0)*25
  const float* ysrc = y1 + bbase + (ptrdiff_t)(t0 - 4) * J_;
  for (int u = tid; u < C_ * 225; u += 256) {
    int c = u / 225, r = (u % 225) * 2;
    float sc = bnp1[c], sh = bnp1[C_ + c];
    const float* p = ysrc + (ptrdiff_t)c * PLANE + r;
    float v0 = 0.f, v1 = 0.f;
    if (r >= rlo && r + 1 < rhi) {
      float2 tv = *(const float2*)p; v0 = tv.x; v1 = tv.y;
    } else {
      if (r >= rlo && r < rhi) v0 = p[0];
      if (r + 1 >= rlo && r + 1 < rhi) v1 = p[1];
    }
    // zero padding must be in z-space (reference pads post-ReLU tensor with 0)
    float z0 = (r >= rlo && r < rhi) ? fmaxf(fmaf(v0, sc, sh), 0.f) : 0.f;
    float z1 = (r + 1 >= rlo && r + 1 < rhi) ? fmaxf(fmaf(v1, sc, sh), 0.f) : 0.f;
    zs[((r << 6) | c) ^ ((r & 7) << 3)] = f2bf(z0);
    zs[(((r + 1) << 6) | c) ^ (((r + 1) & 7) << 3)] = f2bf(z1);
  }
  for (int u = tid; u < 6 * C_; u += 256) {
    int r = 450 + u / C_, c = u % C_;
    zs[((r << 6) | c) ^ ((r & 7) << 3)] = 0;
  }
  __syncthreads();

  int l = tid & 63, w = tid >> 6;
  int lr = l & 15, lh = l >> 4;
  int n0 = w * 64;
  f32x4 acc[4][4];
#pragma unroll
  for (int mf = 0; mf < 4; ++mf)
#pragma unroll
    for (int nf = 0; nf < 4; ++nf) acc[mf][nf] = (f32x4)0.f;

#pragma unroll
  for (int kt = 0; kt < K9; ++kt) {
    bf16x8 af[4][2];
#pragma unroll
    for (int mf = 0; mf < 4; ++mf) {
      const unsigned short* wp = Wb + kt * (C_ * C_) + (mf * 16 + lr) * C_ + lh * 8;
      af[mf][0] = *(const bf16x8*)(wp);
      af[mf][1] = *(const bf16x8*)(wp + 32);
    }
    bf16x8 bfr[4][2];
#pragma unroll
    for (int nf = 0; nf < 4; ++nf) {
      int r = n0 + nf * 16 + lr + 25 * kt;
      int sw = (r & 7) << 3;
      bfr[nf][0] = *(const bf16x8*)&zs[((r << 6) | (lh * 8)) ^ sw];
      bfr[nf][1] = *(const bf16x8*)&zs[((r << 6) | (32 + lh * 8)) ^ sw];
    }
#pragma unroll
    for (int mf = 0; mf < 4; ++mf)
#pragma unroll
      for (int nf = 0; nf < 4; ++nf) {
        acc[mf][nf] = __builtin_amdgcn_mfma_f32_16x16x32_bf16(af[mf][0], bfr[nf][0], acc[mf][nf], 0, 0, 0);
        acc[mf][nf] = __builtin_amdgcn_mfma_f32_16x16x32_bf16(af[mf][1], bfr[nf][1], acc[mf][nf], 0, 0, 0);
      }
  }

  float* ydst = y2 + bbase + (size_t)t0 * J_;
#pragma unroll
  for (int mf = 0; mf < 4; ++mf) {
    float4 tb4 = *(const float4*)(tbias + mf * 16 + 4 * lh);
#pragma unroll
    for (int reg = 0; reg < 4; ++reg) {
      int o = mf * 16 + 4 * lh + reg;
#pragma unroll
      for (int nf = 0; nf < 4; ++nf) {
        int n = n0 + nf * 16 + lr;
        if (n < 250)
          ydst[(size_t)o * PLANE + n] = acc[mf][nf][reg] + ((const float*)&tb4)[reg];
      }
    }
  }
}

// ---------------------------------------------------------------------------
// K5: out = relu(bn2(y2) + x), in place on d_out
__global__ __launch_bounds__(256) void final_kernel(float* __restrict__ y2,
                                                    const float* __restrict__ x,
                                                    const float* __restrict__ bnp2) {
  int i = blockIdx.x * 256 + threadIdx.x;
  if (i >= BCTJ / 4) return;
  int c = (i / (PLANE / 4)) & (C_ - 1);
  float sc = bnp2[c], sh = bnp2[C_ + c];
  float4 v = ((const float4*)y2)[i];
  float4 xv = ((const float4*)x)[i];
  v.x = fmaxf(fmaf(v.x, sc, sh) + xv.x, 0.f);
  v.y = fmaxf(fmaf(v.y, sc, sh) + xv.y, 0.f);
  v.z = fmaxf(fmaf(v.z, sc, sh) + xv.z, 0.f);
  v.w = fmaxf(fmaf(v.w, sc, sh) + xv.w, 0.f);
  ((float4*)y2)[i] = v;
}

// ---------------------------------------------------------------------------
extern "C" void kernel_launch(void* const* d_in, const int* in_sizes, int n_in,
                              void* d_out, int out_size, void* d_ws, size_t ws_size,
                              hipStream_t stream) {
  const float* x     = (const float*)d_in[0];
  const float* A     = (const float*)d_in[1];
  const float* gcn_w = (const float*)d_in[2];
  const float* gcn_b = (const float*)d_in[3];
  const float* bn1_g = (const float*)d_in[4];
  const float* bn1_b = (const float*)d_in[5];
  const float* tcn_w = (const float*)d_in[6];
  const float* tcn_b = (const float*)d_in[7];
  const float* bn2_g = (const float*)d_in[8];
  const float* bn2_b = (const float*)d_in[9];
  float* out = (float*)d_out;

  float* y1 = (float*)d_ws;                               // 15,360,000 f32
  unsigned short* Wb = (unsigned short*)(y1 + BCTJ);      // 36,864 bf16
  unsigned short* Gb = Wb + C_ * C_ * K9;                 // 4,096 bf16
  float* stats = (float*)(Gb + C_ * C_);                  // 256 f32
  float* bnp   = stats + 256;                             // 256 f32

  hipMemsetAsync(stats, 0, 256 * sizeof(float), stream);
  prep_kernel<<<(C_ * C_ * (K9 + 1) + 255) / 256, 256, 0, stream>>>(tcn_w, gcn_w, Wb, Gb);
  gcn_mfma_kernel<<<B_ * (T_ / TTG), 256, 0, stream>>>(x, A, Gb, gcn_b, y1);
  stats_kernel<<<B_ * C_, 256, 0, stream>>>(y1, stats);
  bnparam_kernel<<<1, 64, 0, stream>>>(stats, bn1_g, bn1_b, bnp);
  tcn_mfma_kernel<<<B_ * (T_ / TT), 256, 0, stream>>>(y1, Wb, bnp, tcn_b, out);
  stats_kernel<<<B_ * C_, 256, 0, stream>>>(out, stats + 128);
  bnparam_kernel<<<1, 64, 0, stream>>>(stats + 128, bn2_g, bn2_b, bnp + 128);
  final_kernel<<<BCTJ / 4 / 256, 256, 0, stream>>>(out, x, bnp + 128);
}

// Round 4
// 223.239 us; speedup vs baseline: 3.0969x; 1.3473x over previous
//
#include <hip/hip_runtime.h>

#define B_   32
#define C_   64
#define T_   300
#define J_   25
#define K9   9
constexpr int PLANE = T_ * J_;           // 7500
constexpr int BCTJ  = B_ * C_ * PLANE;   // 15,360,000
constexpr float BN_EPS = 1e-5f;
constexpr float BN_N   = (float)(B_ * T_ * J_);  // 240000

typedef __attribute__((ext_vector_type(8))) short bf16x8;
typedef __attribute__((ext_vector_type(4))) float f32x4;

__device__ inline unsigned short f2bf(float f) {
  unsigned u = __float_as_uint(f);
  unsigned r = (u + 0x7FFF + ((u >> 16) & 1)) >> 16;
  return (unsigned short)r;
}

// ---------------------------------------------------------------------------
// K0: weight prep.
//  [0, 36864)        : tcn_w [o][c][kt] -> Wb[kt][o][c] bf16
//  [36864, 40960)    : gcn_w [o][c]     -> Gb[o][c] bf16
//  [40960, 106496)   : AdT[n][m] = (n<250 && m<250 && n/25==m/25)
//                          ? A[(m%25)][(n%25)] : 0     (bf16, 256x256)
__global__ __launch_bounds__(256) void prep_kernel(const float* __restrict__ tw,
                                                   const float* __restrict__ gw,
                                                   const float* __restrict__ A,
                                                   unsigned short* __restrict__ Wb,
                                                   unsigned short* __restrict__ Gb,
                                                   unsigned short* __restrict__ AdT) {
  int idx = blockIdx.x * 256 + threadIdx.x;
  if (idx < C_ * C_ * K9) {
    int o = idx / (C_ * K9);
    int rem = idx % (C_ * K9);
    int c = rem / K9, kt = rem % K9;
    Wb[kt * (C_ * C_) + o * C_ + c] = f2bf(tw[idx]);
  } else if (idx < C_ * C_ * K9 + C_ * C_) {
    int i = idx - C_ * C_ * K9;
    Gb[i] = f2bf(gw[i]);
  } else if (idx < C_ * C_ * K9 + C_ * C_ + 256 * 256) {
    int i = idx - (C_ * C_ * K9 + C_ * C_);
    int n = i >> 8, m = i & 255;
    float v = 0.f;
    if (n < 250 && m < 250) {
      int tn = n / 25, tm = m / 25;
      if (tn == tm) v = A[(m % 25) * 25 + (n % 25)];
    }
    AdT[i] = f2bf(v);
  }
}

// ---------------------------------------------------------------------------
// K1: GCN via two chained MFMAs. Block = (b, 10-t tile) -> 250 output cols.
//  pass1: XA[c,n] = sum_m Xs[c,m] * AdT[m,n]   (block-diag K, ~42 MFMA/wave)
//  pass2: y1[o,n] = sum_c Gb[o,c] * XA[c,n] + gcn_b[o]
constexpr int TTG = 10;
__global__ __launch_bounds__(256) void gcn_mfma_kernel(
    const float* __restrict__ x, const unsigned short* __restrict__ AdT,
    const unsigned short* __restrict__ Gb, const float* __restrict__ gbias,
    float* __restrict__ y1) {
  __shared__ unsigned short Xs[C_ * 256];     // [c][m] swizzled, 32 KB
  __shared__ unsigned short XAs[256 * C_];    // [n][c] swizzled, 32 KB
  int bid = blockIdx.x;
  int b = bid / (T_ / TTG), tile = bid % (T_ / TTG);
  int t0 = tile * TTG;
  size_t bbase = (size_t)b * (C_ * PLANE);
  int tid = threadIdx.x;

  // ---- stage x tile as bf16 [c][m], XOR-swizzled, cols 250..255 zero ----
  const float* xsrc = x + bbase + (size_t)t0 * J_;
  for (int u = tid; u < C_ * 64; u += 256) {
    int c = u >> 6, qd = u & 63;
    int m = qd * 4;
    float4 v = {0.f, 0.f, 0.f, 0.f};
    if (m < 248) {
      v = *(const float4*)(xsrc + (size_t)c * PLANE + m);
    } else if (m == 248) {
      float2 t2 = *(const float2*)(xsrc + (size_t)c * PLANE + 248);
      v.x = t2.x; v.y = t2.y;
    }
    unsigned p0 = (unsigned)f2bf(v.x) | ((unsigned)f2bf(v.y) << 16);
    unsigned p1 = (unsigned)f2bf(v.z) | ((unsigned)f2bf(v.w) << 16);
    int elem = ((c << 8) | m) ^ ((c & 7) << 3);
    ((unsigned*)Xs)[elem >> 1] = p0;
    ((unsigned*)Xs)[(elem >> 1) + 1] = p1;
  }
  __syncthreads();

  int l = tid & 63, w = tid >> 6;
  int lr = l & 15, lh = l >> 4;
  int n0 = w * 64;

  // ---- pass 1: XA = X * Ad (block-diagonal => skip zero K-chunks) ----
  f32x4 acc1[4][4];
#pragma unroll
  for (int mf = 0; mf < 4; ++mf)
#pragma unroll
    for (int nf = 0; nf < 4; ++nf) acc1[mf][nf] = (f32x4)0.f;

  int qminw = ((n0 / 25) * 25) >> 5;
  int qmaxw = min(7, ((((n0 + 63) / 25) + 1) * 25 - 1) >> 5);
  for (int q = qminw; q <= qmaxw; ++q) {
    bf16x8 afx[4];
#pragma unroll
    for (int mf = 0; mf < 4; ++mf) {
      int c = mf * 16 + lr;
      int elem = ((c << 8) | (q * 32 + lh * 8)) ^ ((c & 7) << 3);
      afx[mf] = *(const bf16x8*)&Xs[elem];
    }
#pragma unroll
    for (int nf = 0; nf < 4; ++nf) {
      int nbase = n0 + nf * 16;
      int tlo = nbase / 25, thi = (nbase + 15) / 25;
      int ql = (tlo * 25) >> 5;
      int qh = min(7, ((thi + 1) * 25 - 1) >> 5);
      if (q < ql || q > qh) continue;
      int n = nbase + lr;
      bf16x8 bfx = *(const bf16x8*)&AdT[n * 256 + q * 32 + lh * 8];
#pragma unroll
      for (int mf = 0; mf < 4; ++mf)
        acc1[mf][nf] = __builtin_amdgcn_mfma_f32_16x16x32_bf16(afx[mf], bfx, acc1[mf][nf], 0, 0, 0);
    }
  }

  // ---- write XA to LDS [n][c] swizzled (feeds pass-2 B-frags) ----
#pragma unroll
  for (int mf = 0; mf < 4; ++mf) {
    int cb = mf * 16 + 4 * lh;
#pragma unroll
    for (int nf = 0; nf < 4; ++nf) {
      int n = n0 + nf * 16 + lr;
      unsigned p0 = (unsigned)f2bf(acc1[mf][nf][0]) | ((unsigned)f2bf(acc1[mf][nf][1]) << 16);
      unsigned p1 = (unsigned)f2bf(acc1[mf][nf][2]) | ((unsigned)f2bf(acc1[mf][nf][3]) << 16);
      int e0 = ((n << 6) | cb) ^ ((n & 7) << 3);
      ((unsigned*)XAs)[e0 >> 1] = p0;
      ((unsigned*)XAs)[(e0 >> 1) + 1] = p1;
    }
  }
  __syncthreads();

  // ---- pass 2: y1 = Gb * XA + bias ----
  f32x4 acc[4][4];
#pragma unroll
  for (int mf = 0; mf < 4; ++mf)
#pragma unroll
    for (int nf = 0; nf < 4; ++nf) acc[mf][nf] = (f32x4)0.f;

  bf16x8 af[4][2];
#pragma unroll
  for (int mf = 0; mf < 4; ++mf) {
    const unsigned short* wp = Gb + (mf * 16 + lr) * C_ + lh * 8;
    af[mf][0] = *(const bf16x8*)(wp);
    af[mf][1] = *(const bf16x8*)(wp + 32);
  }
  bf16x8 bfr[4][2];
#pragma unroll
  for (int nf = 0; nf < 4; ++nf) {
    int r = n0 + nf * 16 + lr;
    int sw = (r & 7) << 3;
    bfr[nf][0] = *(const bf16x8*)&XAs[((r << 6) | (lh * 8)) ^ sw];
    bfr[nf][1] = *(const bf16x8*)&XAs[((r << 6) | (32 + lh * 8)) ^ sw];
  }
#pragma unroll
  for (int mf = 0; mf < 4; ++mf)
#pragma unroll
    for (int nf = 0; nf < 4; ++nf) {
      acc[mf][nf] = __builtin_amdgcn_mfma_f32_16x16x32_bf16(af[mf][0], bfr[nf][0], acc[mf][nf], 0, 0, 0);
      acc[mf][nf] = __builtin_amdgcn_mfma_f32_16x16x32_bf16(af[mf][1], bfr[nf][1], acc[mf][nf], 0, 0, 0);
    }

  float* ydst = y1 + bbase + (size_t)t0 * J_;
#pragma unroll
  for (int mf = 0; mf < 4; ++mf) {
    float4 gb4 = *(const float4*)(gbias + mf * 16 + 4 * lh);
#pragma unroll
    for (int reg = 0; reg < 4; ++reg) {
      int o = mf * 16 + 4 * lh + reg;
#pragma unroll
      for (int nf = 0; nf < 4; ++nf) {
        int n = n0 + nf * 16 + lr;
        if (n < 250)
          ydst[(size_t)o * PLANE + n] = acc[mf][nf][reg] + ((const float*)&gb4)[reg];
      }
    }
  }
}

// ---------------------------------------------------------------------------
// K2: per-channel sum / sumsq over one (b,c) plane
__global__ __launch_bounds__(256) void stats_kernel(const float* __restrict__ in,
                                                    float* __restrict__ stats) {
  int bc = blockIdx.x;
  int c = bc & (C_ - 1);
  const float4* p4 = (const float4*)(in + (size_t)bc * PLANE);
  float s = 0.f, sq = 0.f;
  for (int i = threadIdx.x; i < PLANE / 4; i += 256) {
    float4 v = p4[i];
    s += v.x + v.y + v.z + v.w;
    sq += v.x * v.x + v.y * v.y + v.z * v.z + v.w * v.w;
  }
#pragma unroll
  for (int off = 32; off > 0; off >>= 1) {
    s += __shfl_down(s, off);
    sq += __shfl_down(sq, off);
  }
  __shared__ float ls[2][4];
  int wave = threadIdx.x >> 6, lane = threadIdx.x & 63;
  if (lane == 0) { ls[0][wave] = s; ls[1][wave] = sq; }
  __syncthreads();
  if (threadIdx.x == 0) {
    atomicAdd(&stats[c], ls[0][0] + ls[0][1] + ls[0][2] + ls[0][3]);
    atomicAdd(&stats[C_ + c], ls[1][0] + ls[1][1] + ls[1][2] + ls[1][3]);
  }
}

// ---------------------------------------------------------------------------
// K3: finalize BN params
__global__ void bnparam_kernel(const float* __restrict__ stats,
                               const float* __restrict__ g,
                               const float* __restrict__ b,
                               float* __restrict__ bnp) {
  int c = threadIdx.x;
  if (c < C_) {
    float mean = stats[c] / BN_N;
    float var = stats[C_ + c] / BN_N - mean * mean;
    float inv = rsqrtf(var + BN_EPS);
    float sc = g[c] * inv;
    bnp[c] = sc;
    bnp[C_ + c] = b[c] - mean * sc;
  }
}

// ---------------------------------------------------------------------------
// K4: MFMA temporal conv
constexpr int TT = 10;
constexpr int ZROWS_TOT = 456;           // 450 data + 6 zero pad
__global__ __launch_bounds__(256) void tcn_mfma_kernel(
    const float* __restrict__ y1, const unsigned short* __restrict__ Wb,
    const float* __restrict__ bnp1, const float* __restrict__ tbias,
    float* __restrict__ y2) {
  __shared__ unsigned short zs[ZROWS_TOT * C_];   // 58368 B
  int bid = blockIdx.x;
  int b = bid / (T_ / TT), tile = bid % (T_ / TT);
  int t0 = tile * TT;
  size_t bbase = (size_t)b * (C_ * PLANE);
  int tid = threadIdx.x;

  int rlo = (t0 == 0) ? 100 : 0;
  int rhi = min(450, (304 - t0) * 25);
  const float* ysrc = y1 + bbase + (ptrdiff_t)(t0 - 4) * J_;
  for (int u = tid; u < C_ * 225; u += 256) {
    int c = u / 225, r = (u % 225) * 2;
    float sc = bnp1[c], sh = bnp1[C_ + c];
    const float* p = ysrc + (ptrdiff_t)c * PLANE + r;
    float v0 = 0.f, v1 = 0.f;
    if (r >= rlo && r + 1 < rhi) {
      float2 tv = *(const float2*)p; v0 = tv.x; v1 = tv.y;
    } else {
      if (r >= rlo && r < rhi) v0 = p[0];
      if (r + 1 >= rlo && r + 1 < rhi) v1 = p[1];
    }
    float z0 = (r >= rlo && r < rhi) ? fmaxf(fmaf(v0, sc, sh), 0.f) : 0.f;
    float z1 = (r + 1 >= rlo && r + 1 < rhi) ? fmaxf(fmaf(v1, sc, sh), 0.f) : 0.f;
    zs[((r << 6) | c) ^ ((r & 7) << 3)] = f2bf(z0);
    zs[(((r + 1) << 6) | c) ^ (((r + 1) & 7) << 3)] = f2bf(z1);
  }
  for (int u = tid; u < 6 * C_; u += 256) {
    int r = 450 + u / C_, c = u % C_;
    zs[((r << 6) | c) ^ ((r & 7) << 3)] = 0;
  }
  __syncthreads();

  int l = tid & 63, w = tid >> 6;
  int lr = l & 15, lh = l >> 4;
  int n0 = w * 64;
  f32x4 acc[4][4];
#pragma unroll
  for (int mf = 0; mf < 4; ++mf)
#pragma unroll
    for (int nf = 0; nf < 4; ++nf) acc[mf][nf] = (f32x4)0.f;

#pragma unroll
  for (int kt = 0; kt < K9; ++kt) {
    bf16x8 af[4][2];
#pragma unroll
    for (int mf = 0; mf < 4; ++mf) {
      const unsigned short* wp = Wb + kt * (C_ * C_) + (mf * 16 + lr) * C_ + lh * 8;
      af[mf][0] = *(const bf16x8*)(wp);
      af[mf][1] = *(const bf16x8*)(wp + 32);
    }
    bf16x8 bfr[4][2];
#pragma unroll
    for (int nf = 0; nf < 4; ++nf) {
      int r = n0 + nf * 16 + lr + 25 * kt;
      int sw = (r & 7) << 3;
      bfr[nf][0] = *(const bf16x8*)&zs[((r << 6) | (lh * 8)) ^ sw];
      bfr[nf][1] = *(const bf16x8*)&zs[((r << 6) | (32 + lh * 8)) ^ sw];
    }
#pragma unroll
    for (int mf = 0; mf < 4; ++mf)
#pragma unroll
      for (int nf = 0; nf < 4; ++nf) {
        acc[mf][nf] = __builtin_amdgcn_mfma_f32_16x16x32_bf16(af[mf][0], bfr[nf][0], acc[mf][nf], 0, 0, 0);
        acc[mf][nf] = __builtin_amdgcn_mfma_f32_16x16x32_bf16(af[mf][1], bfr[nf][1], acc[mf][nf], 0, 0, 0);
      }
  }

  float* ydst = y2 + bbase + (size_t)t0 * J_;
#pragma unroll
  for (int mf = 0; mf < 4; ++mf) {
    float4 tb4 = *(const float4*)(tbias + mf * 16 + 4 * lh);
#pragma unroll
    for (int reg = 0; reg < 4; ++reg) {
      int o = mf * 16 + 4 * lh + reg;
#pragma unroll
      for (int nf = 0; nf < 4; ++nf) {
        int n = n0 + nf * 16 + lr;
        if (n < 250)
          ydst[(size_t)o * PLANE + n] = acc[mf][nf][reg] + ((const float*)&tb4)[reg];
      }
    }
  }
}

// ---------------------------------------------------------------------------
// K5: out = relu(bn2(y2) + x), in place on d_out
__global__ __launch_bounds__(256) void final_kernel(float* __restrict__ y2,
                                                    const float* __restrict__ x,
                                                    const float* __restrict__ bnp2) {
  int i = blockIdx.x * 256 + threadIdx.x;
  if (i >= BCTJ / 4) return;
  int c = (i / (PLANE / 4)) & (C_ - 1);
  float sc = bnp2[c], sh = bnp2[C_ + c];
  float4 v = ((const float4*)y2)[i];
  float4 xv = ((const float4*)x)[i];
  v.x = fmaxf(fmaf(v.x, sc, sh) + xv.x, 0.f);
  v.y = fmaxf(fmaf(v.y, sc, sh) + xv.y, 0.f);
  v.z = fmaxf(fmaf(v.z, sc, sh) + xv.z, 0.f);
  v.w = fmaxf(fmaf(v.w, sc, sh) + xv.w, 0.f);
  ((float4*)y2)[i] = v;
}

// ---------------------------------------------------------------------------
extern "C" void kernel_launch(void* const* d_in, const int* in_sizes, int n_in,
                              void* d_out, int out_size, void* d_ws, size_t ws_size,
                              hipStream_t stream) {
  const float* x     = (const float*)d_in[0];
  const float* A     = (const float*)d_in[1];
  const float* gcn_w = (const float*)d_in[2];
  const float* gcn_b = (const float*)d_in[3];
  const float* bn1_g = (const float*)d_in[4];
  const float* bn1_b = (const float*)d_in[5];
  const float* tcn_w = (const float*)d_in[6];
  const float* tcn_b = (const float*)d_in[7];
  const float* bn2_g = (const float*)d_in[8];
  const float* bn2_b = (const float*)d_in[9];
  float* out = (float*)d_out;

  float* y1 = (float*)d_ws;                               // 15,360,000 f32
  unsigned short* Wb  = (unsigned short*)(y1 + BCTJ);     // 36,864 bf16
  unsigned short* Gb  = Wb + C_ * C_ * K9;                // 4,096 bf16
  unsigned short* AdT = Gb + C_ * C_;                     // 65,536 bf16
  float* stats = (float*)(AdT + 256 * 256);               // 256 f32
  float* bnp   = stats + 256;                             // 256 f32

  hipMemsetAsync(stats, 0, 256 * sizeof(float), stream);
  int prep_n = C_ * C_ * K9 + C_ * C_ + 256 * 256;
  prep_kernel<<<(prep_n + 255) / 256, 256, 0, stream>>>(tcn_w, gcn_w, A, Wb, Gb, AdT);
  gcn_mfma_kernel<<<B_ * (T_ / TTG), 256, 0, stream>>>(x, AdT, Gb, gcn_b, y1);
  stats_kernel<<<B_ * C_, 256, 0, stream>>>(y1, stats);
  bnparam_kernel<<<1, 64, 0, stream>>>(stats, bn1_g, bn1_b, bnp);
  tcn_mfma_kernel<<<B_ * (T_ / TT), 256, 0, stream>>>(y1, Wb, bnp, tcn_b, out);
  stats_kernel<<<B_ * C_, 256, 0, stream>>>(out, stats + 128);
  bnparam_kernel<<<1, 64, 0, stream>>>(stats + 128, bn2_g, bn2_b, bnp + 128);
  final_kernel<<<BCTJ / 4 / 256, 256, 0, stream>>>(out, x, bnp + 128);
}